// Round 10
// baseline (181.111 us; speedup 1.0000x reference)
//
#include <hip/hip_runtime.h>

// out[n,k] = <Cmat[k], project[n]> + d[k]   (pipeline is fully linear in project)
// Cms[(s,k)][r] = segment-major fold of spread(w_head)·(w3·w2·w1).
//
// k_main: 784 blocks (98 s x 8), ALL co-resident (40KB LDS, <=128 VGPR).
// Block b: s=b>>3; stage contiguous 40KB slice ONCE (one barrier total),
// then 4 g-items x (4 waves x 4 n) against the same LDS slice.
// Epilogue: full-wave shfl_xor reduce + predicated store (no LDS, no barrier).
//
// ws layout (floats):
//   W23   [512][512]     off 0
//   W123  [512][512]     off 262144
//   WH    [490][512]     off 524288
//   Bmat  [490][512]     off 775168
//   Cms   [98][10][1024] off 1026048
//   vvec  [512]          off 2029568
//   dpart [10][8]        off 2030080
//   part  [98][512][10]  off 2030160

#define CHW 100352   // 512*196
#define CHW4 25088
#define NSEG 98
#define SEG 1024
#define SEGV 256
#define STEP 1.8571428571428572f  // 13/7

__device__ __forceinline__ float edge_w(int p, float s, int lim) {
    float f = floorf(s);
    float wfrac = s - f;
    int a = (int)f;
    int b = a + 1;
    a = min(max(a, 0), lim); b = min(max(b, 0), lim);
    float c = 0.f;
    if (p == a) c += 1.f - wfrac;
    if (p == b) c += wfrac;
    return c;
}

// C[M x 512] = A[M x 512] * B[512 x 512]; 32x32 tile per block, thread = 2x2.
__global__ __launch_bounds__(256) void k_mm32(const float* __restrict__ A,
                                              const float* __restrict__ B,
                                              float* __restrict__ C, int M) {
    __shared__ float As[32][36];
    __shared__ float Bs[32][36];
    int bx = blockIdx.x, by = blockIdx.y;
    int tid = threadIdx.x;
    int lr = tid >> 3;          // 0..31
    int lc = (tid & 7) << 2;    // 0,4,..,28
    int tx = tid & 15, ty = tid >> 4;
    float a00 = 0.f, a01 = 0.f, a10 = 0.f, a11 = 0.f;
    for (int kc = 0; kc < 512; kc += 32) {
        int gr = by * 32 + lr;
        float4 av = make_float4(0.f, 0.f, 0.f, 0.f);
        if (gr < M) av = *(const float4*)&A[(size_t)gr * 512 + kc + lc];
        *(float4*)&As[lr][lc] = av;
        float4 bv = *(const float4*)&B[(size_t)(kc + lr) * 512 + bx * 32 + lc];
        *(float4*)&Bs[lr][lc] = bv;
        __syncthreads();
        #pragma unroll
        for (int kk = 0; kk < 32; ++kk) {
            float b0 = Bs[kk][tx * 2], b1 = Bs[kk][tx * 2 + 1];
            float x0 = As[ty * 2][kk], x1 = As[ty * 2 + 1][kk];
            a00 += x0 * b0; a01 += x0 * b1;
            a10 += x1 * b0; a11 += x1 * b1;
        }
        __syncthreads();
    }
    int r0 = by * 32 + ty * 2, c0 = bx * 32 + tx * 2;
    if (r0 < M)     { C[(size_t)r0 * 512 + c0] = a00; C[(size_t)r0 * 512 + c0 + 1] = a01; }
    if (r0 + 1 < M) { C[(size_t)(r0 + 1) * 512 + c0] = a10; C[(size_t)(r0 + 1) * 512 + c0 + 1] = a11; }
}

// WH[r][q] = wh[k][q*49 + ji],  r = k*49 + ji
__global__ void k_whT(const float* __restrict__ w_note, const float* __restrict__ w_reg,
                      float* __restrict__ WH) {
    int r = blockIdx.x;      // 0..489
    int q = threadIdx.x;     // 0..511
    int k = r / 49, ji = r % 49;
    const float* wh = (k < 2) ? (w_note + k * 25088) : (w_reg + (k - 2) * 25088);
    WH[(size_t)r * 512 + q] = wh[q * 49 + ji];
}

// Cms[((chw>>10)*10 + k)*1024 + (chw&1023)] = sum_ji cy*cx * Bmat[(k*49+ji)*512+c]
// with chw = c*196 + hw  (segment-major layout for contiguous k_main staging)
__global__ void k_spread2(const float* __restrict__ Bmat, float* __restrict__ Cms) {
    int c = blockIdx.x;      // 0..511
    int k = blockIdx.y;      // 0..9
    int hw = threadIdx.x;    // 0..195
    int h = hw / 14, w = hw % 14;
    const float base = STEP * 0.5f - 0.5f;
    float acc = 0.f;
    for (int j = 0; j < 7; ++j) {
        float cy = edge_w(h, base + j * STEP, 13);
        if (cy == 0.f) continue;
        for (int i = 0; i < 7; ++i) {
            float cx = edge_w(w, base + i * STEP, 13);
            if (cx != 0.f) acc += cy * cx * Bmat[(size_t)(k * 49 + j * 7 + i) * 512 + c];
        }
    }
    int chw = c * 196 + hw;
    int s = chw >> 10, r = chw & 1023;
    Cms[((size_t)s * 10 + k) * 1024 + r] = acc;
}

// vvec[q] = b3[q] + sum_p w3[q][p]*b2[p] + sum_o W23[q][o]*b1[o]
__global__ void k_bvec(const float* __restrict__ w3, const float* __restrict__ W23,
                       const float* __restrict__ b1, const float* __restrict__ b2,
                       const float* __restrict__ b3, float* __restrict__ vvec) {
    int o = blockIdx.x;
    int l = threadIdx.x;  // 64
    float s = 0.f;
    for (int i = l; i < 512; i += 64)
        s += w3[o * 512 + i] * b2[i] + W23[o * 512 + i] * b1[i];
    for (int off = 32; off; off >>= 1) s += __shfl_down(s, off);
    if (l == 0) vvec[o] = b3[o] + s;
}

// dpart[k][b] = partial of sum_i wh[k][i] * vvec[i/49]
__global__ void k_dvec(const float* __restrict__ w_note, const float* __restrict__ w_reg,
                       const float* __restrict__ vvec, float* __restrict__ dpart) {
    int k = blockIdx.x;   // 10
    int b = blockIdx.y;   // 8
    int t = threadIdx.x;  // 256
    const float* wh = (k < 2) ? (w_note + k * 25088) : (w_reg + (k - 2) * 25088);
    float s = 0.f;
    for (int i = b * 256 + t; i < 25088; i += 2048) s += wh[i] * vvec[i / 49];
    __shared__ float red[256];
    red[t] = s;
    __syncthreads();
    for (int off = 128; off; off >>= 1) {
        if (t < off) red[t] += red[t + off];
        __syncthreads();
    }
    if (t == 0) dpart[k * 8 + b] = red[0];
}

// Block b: s = b>>3, g0 = (b&7)*4. Stage slice once; 4 g-items reuse it.
__global__ __launch_bounds__(256) void k_main(const float* __restrict__ proj,
                                              const float* __restrict__ Cms,
                                              float* __restrict__ part) {
    __shared__ float4 cml[10 * SEGV];   // 40,960 B
    int b = blockIdx.x;          // 0..783
    int s = b >> 3;              // 0..97
    int g0 = (b & 7) << 2;       // 0,4,..,28
    int tid = threadIdx.x;
    int wv = tid >> 6, lane = tid & 63;

    const float4* cg = (const float4*)Cms + (size_t)s * (10 * SEGV);
    #pragma unroll
    for (int i = 0; i < 10; ++i)
        cml[i * 256 + tid] = cg[i * 256 + tid];
    __syncthreads();

    const float4* pg = (const float4*)proj + (size_t)s * SEGV + lane;

    #pragma unroll 1
    for (int gi = 0; gi < 4; ++gi) {
        int n0 = (g0 + gi) * 16 + wv * 4;
        const float4* p0 = pg + (size_t)n0 * CHW4;
        const float4* p1 = p0 + CHW4;
        const float4* p2 = p1 + CHW4;
        const float4* p3 = p2 + CHW4;

        float acc[4][10];
        #pragma unroll
        for (int j = 0; j < 4; ++j)
            #pragma unroll
            for (int k = 0; k < 10; ++k) acc[j][k] = 0.f;

        float4 pa = p0[0], pb = p1[0], pc = p2[0], pd = p3[0];
        #pragma unroll 1
        for (int it = 0; it < 4; ++it) {
            float4 na, nb, nc, nd;
            if (it < 3) {
                na = p0[(it + 1) * 64]; nb = p1[(it + 1) * 64];
                nc = p2[(it + 1) * 64]; nd = p3[(it + 1) * 64];
            }
            #pragma unroll
            for (int k = 0; k < 10; ++k) {
                float4 c = cml[k * 256 + it * 64 + lane];
                acc[0][k] += pa.x * c.x + pa.y * c.y + pa.z * c.z + pa.w * c.w;
                acc[1][k] += pb.x * c.x + pb.y * c.y + pb.z * c.z + pb.w * c.w;
                acc[2][k] += pc.x * c.x + pc.y * c.y + pc.z * c.z + pc.w * c.w;
                acc[3][k] += pd.x * c.x + pd.y * c.y + pd.z * c.z + pd.w * c.w;
            }
            if (it < 3) { pa = na; pb = nb; pc = nc; pd = nd; }
        }

        // full-wave butterfly reduce; value (j,k) stored by lane j*10+k
        #pragma unroll
        for (int j = 0; j < 4; ++j)
            #pragma unroll
            for (int k = 0; k < 10; ++k) {
                float v = acc[j][k];
                v += __shfl_xor(v, 1);
                v += __shfl_xor(v, 2);
                v += __shfl_xor(v, 4);
                v += __shfl_xor(v, 8);
                v += __shfl_xor(v, 16);
                v += __shfl_xor(v, 32);
                if (lane == j * 10 + k)
                    part[((size_t)s * 512 + n0 + j) * 10 + k] = v;
            }
    }
}

__global__ void k_reduce(const float* __restrict__ part,
                         const float* __restrict__ dpart,
                         const float* __restrict__ b_note, const float* __restrict__ b_reg,
                         float* __restrict__ out) {
    int idx = blockIdx.x * 256 + threadIdx.x;  // 0..5119
    int n = idx / 10, k = idx % 10;
    float s = (k < 2) ? b_note[k] : b_reg[k - 2];
    for (int b = 0; b < 8; ++b) s += dpart[k * 8 + b];
    for (int seg = 0; seg < NSEG; ++seg) s += part[((size_t)seg * 512 + n) * 10 + k];
    if (k < 2) out[n * 2 + k] = s;
    else       out[1024 + n * 8 + (k - 2)] = s;
}

extern "C" void kernel_launch(void* const* d_in, const int* in_sizes, int n_in,
                              void* d_out, int out_size, void* d_ws, size_t ws_size,
                              hipStream_t stream) {
    const float* proj   = (const float*)d_in[0];
    const float* w1     = (const float*)d_in[1];
    const float* b1     = (const float*)d_in[2];
    const float* w2     = (const float*)d_in[3];
    const float* b2     = (const float*)d_in[4];
    const float* w3     = (const float*)d_in[5];
    const float* b3     = (const float*)d_in[6];
    const float* w_note = (const float*)d_in[7];
    const float* b_note = (const float*)d_in[8];
    const float* w_reg  = (const float*)d_in[9];
    const float* b_reg  = (const float*)d_in[10];

    float* ws    = (float*)d_ws;
    float* W23   = ws;
    float* W123  = W23 + 262144;
    float* WH    = W123 + 262144;
    float* Bmat  = WH + 250880;
    float* Cms   = Bmat + 250880;
    float* vvec  = Cms + 1003520;
    float* dpart = vvec + 512;
    float* part  = dpart + 80;
    float* out   = (float*)d_out;

    k_mm32<<<dim3(16, 16), 256, 0, stream>>>(w3, w2, W23, 512);
    k_mm32<<<dim3(16, 16), 256, 0, stream>>>(W23, w1, W123, 512);
    k_whT<<<490, 512, 0, stream>>>(w_note, w_reg, WH);
    k_mm32<<<dim3(16, 16), 256, 0, stream>>>(WH, W123, Bmat, 490);
    k_spread2<<<dim3(512, 10), 196, 0, stream>>>(Bmat, Cms);
    k_bvec<<<512, 64, 0, stream>>>(w3, W23, b1, b2, b3, vvec);
    k_dvec<<<dim3(10, 8), 256, 0, stream>>>(w_note, w_reg, vvec, dpart);
    k_main<<<784, 256, 0, stream>>>(proj, Cms, part);
    k_reduce<<<20, 256, 0, stream>>>(part, dpart, b_note, b_reg, out);
}

// Round 11
// 126.703 us; speedup vs baseline: 1.4294x; 1.4294x over previous
//
#include <hip/hip_runtime.h>

// out[n,k] = <Cmat[k], project[n]> + d[k]   (pipeline is fully linear in project)
// Cm[k][c*196+hw] = spread-fold of WH·(w3·w2·w1).
//
// k_main (NEW): no LDS. 512 blocks (128 n-groups x 4 c4-quarters), all
// co-resident. Block walks its contiguous quarter-row linearly (24.5 windows
// of 256 float4), 4 consecutive n-rows per thread, Cmat read from L2
// (4 MB, ~128x reuse). One butterfly reduce per kernel.
//
// ws layout (floats):
//   W23   [512][512]     off 0
//   W123  [512][512]     off 262144
//   WH    [490][512]     off 524288
//   Bmat  [490][512]     off 775168
//   Cm    [10][CHW]      off 1026048
//   vvec  [512]          off 2029568
//   dpart [10][8]        off 2030080
//   part  [128*16][40]   off 2030160

#define CHW 100352   // 512*196
#define CHW4 25088
#define QW 6272      // c4 per quarter-row (CHW4/4)
#define STEP 1.8571428571428572f  // 13/7

__device__ __forceinline__ float edge_w(int p, float s, int lim) {
    float f = floorf(s);
    float wfrac = s - f;
    int a = (int)f;
    int b = a + 1;
    a = min(max(a, 0), lim); b = min(max(b, 0), lim);
    float c = 0.f;
    if (p == a) c += 1.f - wfrac;
    if (p == b) c += wfrac;
    return c;
}

// C[M x 512] = A[M x 512] * B[512 x 512]; 32x32 tile per block, thread = 2x2.
__global__ __launch_bounds__(256) void k_mm32(const float* __restrict__ A,
                                              const float* __restrict__ B,
                                              float* __restrict__ C, int M) {
    __shared__ float As[32][36];
    __shared__ float Bs[32][36];
    int bx = blockIdx.x, by = blockIdx.y;
    int tid = threadIdx.x;
    int lr = tid >> 3;          // 0..31
    int lc = (tid & 7) << 2;    // 0,4,..,28
    int tx = tid & 15, ty = tid >> 4;
    float a00 = 0.f, a01 = 0.f, a10 = 0.f, a11 = 0.f;
    for (int kc = 0; kc < 512; kc += 32) {
        int gr = by * 32 + lr;
        float4 av = make_float4(0.f, 0.f, 0.f, 0.f);
        if (gr < M) av = *(const float4*)&A[(size_t)gr * 512 + kc + lc];
        *(float4*)&As[lr][lc] = av;
        float4 bv = *(const float4*)&B[(size_t)(kc + lr) * 512 + bx * 32 + lc];
        *(float4*)&Bs[lr][lc] = bv;
        __syncthreads();
        #pragma unroll
        for (int kk = 0; kk < 32; ++kk) {
            float b0 = Bs[kk][tx * 2], b1 = Bs[kk][tx * 2 + 1];
            float x0 = As[ty * 2][kk], x1 = As[ty * 2 + 1][kk];
            a00 += x0 * b0; a01 += x0 * b1;
            a10 += x1 * b0; a11 += x1 * b1;
        }
        __syncthreads();
    }
    int r0 = by * 32 + ty * 2, c0 = bx * 32 + tx * 2;
    if (r0 < M)     { C[(size_t)r0 * 512 + c0] = a00; C[(size_t)r0 * 512 + c0 + 1] = a01; }
    if (r0 + 1 < M) { C[(size_t)(r0 + 1) * 512 + c0] = a10; C[(size_t)(r0 + 1) * 512 + c0 + 1] = a11; }
}

// WH[r][q] = wh[k][q*49 + ji],  r = k*49 + ji
__global__ void k_whT(const float* __restrict__ w_note, const float* __restrict__ w_reg,
                      float* __restrict__ WH) {
    int r = blockIdx.x;      // 0..489
    int q = threadIdx.x;     // 0..511
    int k = r / 49, ji = r % 49;
    const float* wh = (k < 2) ? (w_note + k * 25088) : (w_reg + (k - 2) * 25088);
    WH[(size_t)r * 512 + q] = wh[q * 49 + ji];
}

// Cm[k*CHW + c*196 + hw] = sum_ji cy(j,h)*cx(i,w) * Bmat[(k*49+ji)*512 + c]
__global__ void k_spread2(const float* __restrict__ Bmat, float* __restrict__ Cm) {
    int c = blockIdx.x;      // 0..511
    int k = blockIdx.y;      // 0..9
    int hw = threadIdx.x;    // 0..195
    int h = hw / 14, w = hw % 14;
    const float base = STEP * 0.5f - 0.5f;
    float acc = 0.f;
    for (int j = 0; j < 7; ++j) {
        float cy = edge_w(h, base + j * STEP, 13);
        if (cy == 0.f) continue;
        for (int i = 0; i < 7; ++i) {
            float cx = edge_w(w, base + i * STEP, 13);
            if (cx != 0.f) acc += cy * cx * Bmat[(size_t)(k * 49 + j * 7 + i) * 512 + c];
        }
    }
    Cm[(size_t)k * CHW + c * 196 + hw] = acc;
}

// vvec[q] = b3[q] + sum_p w3[q][p]*b2[p] + sum_o W23[q][o]*b1[o]
__global__ void k_bvec(const float* __restrict__ w3, const float* __restrict__ W23,
                       const float* __restrict__ b1, const float* __restrict__ b2,
                       const float* __restrict__ b3, float* __restrict__ vvec) {
    int o = blockIdx.x;
    int l = threadIdx.x;  // 64
    float s = 0.f;
    for (int i = l; i < 512; i += 64)
        s += w3[o * 512 + i] * b2[i] + W23[o * 512 + i] * b1[i];
    for (int off = 32; off; off >>= 1) s += __shfl_down(s, off);
    if (l == 0) vvec[o] = b3[o] + s;
}

// dpart[k][b] = partial of sum_i wh[k][i] * vvec[i/49]
__global__ void k_dvec(const float* __restrict__ w_note, const float* __restrict__ w_reg,
                       const float* __restrict__ vvec, float* __restrict__ dpart) {
    int k = blockIdx.x;   // 10
    int b = blockIdx.y;   // 8
    int t = threadIdx.x;  // 256
    const float* wh = (k < 2) ? (w_note + k * 25088) : (w_reg + (k - 2) * 25088);
    float s = 0.f;
    for (int i = b * 256 + t; i < 25088; i += 2048) s += wh[i] * vvec[i / 49];
    __shared__ float red[256];
    red[t] = s;
    __syncthreads();
    for (int off = 128; off; off >>= 1) {
        if (t < off) red[t] += red[t + off];
        __syncthreads();
    }
    if (t == 0) dpart[k * 8 + b] = red[0];
}

// Block b: g = b>>2 (4 rows n=g*4..g*4+3), xb = b&3 (quarter-row).
// Walk 24 full windows + 128-wide tail; Cmat from L2; one reduce at end.
__global__ __launch_bounds__(256) void k_main(const float* __restrict__ proj,
                                              const float* __restrict__ Cm,
                                              float* __restrict__ part) {
    int b = blockIdx.x;          // 0..511
    int g = b >> 2;              // 0..127
    int xb = b & 3;              // 0..3
    int tid = threadIdx.x;
    int wv = tid >> 6, lane = tid & 63;

    const float4* pg = (const float4*)proj;
    const float4* cg = (const float4*)Cm;
    int base = xb * QW;          // c4 offset of this quarter
    const float4* p0 = pg + (size_t)(g * 4 + 0) * CHW4 + base + tid;
    const float4* p1 = pg + (size_t)(g * 4 + 1) * CHW4 + base + tid;
    const float4* p2 = pg + (size_t)(g * 4 + 2) * CHW4 + base + tid;
    const float4* p3 = pg + (size_t)(g * 4 + 3) * CHW4 + base + tid;
    const float4* cb = cg + base + tid;

    float acc[4][10];
    #pragma unroll
    for (int j = 0; j < 4; ++j)
        #pragma unroll
        for (int k = 0; k < 10; ++k) acc[j][k] = 0.f;

    float4 pa = p0[0], pb = p1[0], pc = p2[0], pd = p3[0];

    #pragma unroll 1
    for (int it = 0; it < 24; ++it) {
        float4 na, nb, nc, nd;
        bool nv = (it < 23) || (tid < 128);
        int noff = (it + 1) * 256;
        if (nv) { na = p0[noff]; nb = p1[noff]; nc = p2[noff]; nd = p3[noff]; }
        #pragma unroll
        for (int k = 0; k < 10; ++k) {
            float4 c = cb[(size_t)k * CHW4 + it * 256];
            acc[0][k] += pa.x * c.x + pa.y * c.y + pa.z * c.z + pa.w * c.w;
            acc[1][k] += pb.x * c.x + pb.y * c.y + pb.z * c.z + pb.w * c.w;
            acc[2][k] += pc.x * c.x + pc.y * c.y + pc.z * c.z + pc.w * c.w;
            acc[3][k] += pd.x * c.x + pd.y * c.y + pd.z * c.z + pd.w * c.w;
        }
        if (nv) { pa = na; pb = nb; pc = nc; pd = nd; }
    }
    // tail window: c4 offset 24*256, width 128 (threads 0..127 hold valid data)
    if (tid < 128) {
        #pragma unroll
        for (int k = 0; k < 10; ++k) {
            float4 c = cb[(size_t)k * CHW4 + 24 * 256];
            acc[0][k] += pa.x * c.x + pa.y * c.y + pa.z * c.z + pa.w * c.w;
            acc[1][k] += pb.x * c.x + pb.y * c.y + pb.z * c.z + pb.w * c.w;
            acc[2][k] += pc.x * c.x + pc.y * c.y + pc.z * c.z + pc.w * c.w;
            acc[3][k] += pd.x * c.x + pd.y * c.y + pd.z * c.z + pd.w * c.w;
        }
    }

    // one butterfly reduce; lane j*10+k stores value (j,k)
    #pragma unroll
    for (int j = 0; j < 4; ++j)
        #pragma unroll
        for (int k = 0; k < 10; ++k) {
            float v = acc[j][k];
            v += __shfl_xor(v, 1);
            v += __shfl_xor(v, 2);
            v += __shfl_xor(v, 4);
            v += __shfl_xor(v, 8);
            v += __shfl_xor(v, 16);
            v += __shfl_xor(v, 32);
            if (lane == j * 10 + k)
                part[((size_t)g * 16 + xb * 4 + wv) * 40 + j * 10 + k] = v;
        }
}

__global__ void k_reduce(const float* __restrict__ part,
                         const float* __restrict__ dpart,
                         const float* __restrict__ b_note, const float* __restrict__ b_reg,
                         float* __restrict__ out) {
    int idx = blockIdx.x * 256 + threadIdx.x;  // 0..5119
    int n = idx / 10, k = idx % 10;
    int g = n >> 2, j = n & 3;
    float s = (k < 2) ? b_note[k] : b_reg[k - 2];
    for (int b = 0; b < 8; ++b) s += dpart[k * 8 + b];
    for (int w = 0; w < 16; ++w) s += part[((size_t)g * 16 + w) * 40 + j * 10 + k];
    if (k < 2) out[n * 2 + k] = s;
    else       out[1024 + n * 8 + (k - 2)] = s;
}

extern "C" void kernel_launch(void* const* d_in, const int* in_sizes, int n_in,
                              void* d_out, int out_size, void* d_ws, size_t ws_size,
                              hipStream_t stream) {
    const float* proj   = (const float*)d_in[0];
    const float* w1     = (const float*)d_in[1];
    const float* b1     = (const float*)d_in[2];
    const float* w2     = (const float*)d_in[3];
    const float* b2     = (const float*)d_in[4];
    const float* w3     = (const float*)d_in[5];
    const float* b3     = (const float*)d_in[6];
    const float* w_note = (const float*)d_in[7];
    const float* b_note = (const float*)d_in[8];
    const float* w_reg  = (const float*)d_in[9];
    const float* b_reg  = (const float*)d_in[10];

    float* ws    = (float*)d_ws;
    float* W23   = ws;
    float* W123  = W23 + 262144;
    float* WH    = W123 + 262144;
    float* Bmat  = WH + 250880;
    float* Cm    = Bmat + 250880;
    float* vvec  = Cm + 1003520;
    float* dpart = vvec + 512;
    float* part  = dpart + 80;
    float* out   = (float*)d_out;

    k_mm32<<<dim3(16, 16), 256, 0, stream>>>(w3, w2, W23, 512);
    k_mm32<<<dim3(16, 16), 256, 0, stream>>>(W23, w1, W123, 512);
    k_whT<<<490, 512, 0, stream>>>(w_note, w_reg, WH);
    k_mm32<<<dim3(16, 16), 256, 0, stream>>>(WH, W123, Bmat, 490);
    k_spread2<<<dim3(512, 10), 196, 0, stream>>>(Bmat, Cm);
    k_bvec<<<512, 64, 0, stream>>>(w3, W23, b1, b2, b3, vvec);
    k_dvec<<<dim3(10, 8), 256, 0, stream>>>(w_note, w_reg, vvec, dpart);
    k_main<<<512, 256, 0, stream>>>(proj, Cm, part);
    k_reduce<<<20, 256, 0, stream>>>(part, dpart, b_note, b_reg, out);
}